// Round 6
// baseline (167.008 us; speedup 1.0000x reference)
//
#include <hip/hip_runtime.h>
#include <math.h>

#define S_LEN 2048
#define B_SZ 2

typedef __bf16 bf16_8 __attribute__((ext_vector_type(8)));
typedef float  f32_4  __attribute__((ext_vector_type(4)));

__device__ __forceinline__ unsigned short ftob(float f) {
  union { __bf16 h; unsigned short u; } cv;
  cv.h = (__bf16)f;              // fptrunc -> RNE
  return cv.u;
}

// async global->LDS, 16B per lane. LDS dest must be wave-uniform base + lane*16.
__device__ __forceinline__ void gll16(const unsigned short* g, unsigned short* l) {
  __builtin_amdgcn_global_load_lds(
      (const __attribute__((address_space(1))) unsigned int*)g,
      (__attribute__((address_space(3))) unsigned int*)l, 16, 0, 0);
}

// fold 1/sqrt(64) * log2(e) into Q at projection -> softmax in exp2 domain
#define QSCALE (0.125f * 1.44269504f)

// K/V tile images: dense 64x64 bf16 (4096 shorts = 8 KB), 16B-chunk XOR
// swizzle: element (row, col) at row*64 + ((col>>3) ^ (row&7))*8 + (col&7).
// V image rows = d, cols = key (natural order).
// K image rows are PERMUTED keys: image row mt*16 + q*4 + r holds key
// 32*(mt>>1) + q*8 + (mt&1)*4 + r. With this ordering the QK^T C-layout
// (keys at quad*4+r per z[mt]) packs DIRECTLY into the PV B-frag layout
// (keys at quad*8+j) lane-locally -> no P LDS roundtrip at all.

// ---------------------------------------------------------------------------
// 32x32 transpose+convert tile helper: W[K=1024][N] fp32 -> Wt[N][1024] bf16.
// ---------------------------------------------------------------------------
__device__ __forceinline__ void tr_tile(const float* __restrict__ W,
                                        unsigned short* __restrict__ Wt,
                                        int N, int bx, int by, float (*T)[33])
{
  const int k0 = by * 32, n0 = bx * 32;
  const int r = threadIdx.x >> 3, c4 = (threadIdx.x & 7) * 4;
  const float4 v = *(const float4*)&W[(size_t)(k0 + r) * N + n0 + c4];
  T[r][c4 + 0] = v.x; T[r][c4 + 1] = v.y;
  T[r][c4 + 2] = v.z; T[r][c4 + 3] = v.w;
  __syncthreads();
  ushort4 o;
  o.x = ftob(T[c4 + 0][r]); o.y = ftob(T[c4 + 1][r]);
  o.z = ftob(T[c4 + 2][r]); o.w = ftob(T[c4 + 3][r]);
  *(ushort4*)&Wt[(size_t)(n0 + r) * 1024 + k0 + c4] = o;
}

// ---------------------------------------------------------------------------
// prep: [0,1024) wq->wqkvt | [1024,1280) wk | [1280,1536) wv |
//       [1536,2560) wo->wot | [2560,3584) x fp32->bf16
// ---------------------------------------------------------------------------
__global__ __launch_bounds__(256) void prep(
    const float* __restrict__ x, const float* __restrict__ wq,
    const float* __restrict__ wk, const float* __restrict__ wv,
    const float* __restrict__ wo,
    unsigned short* __restrict__ xb, unsigned short* __restrict__ wqkvt,
    unsigned short* __restrict__ wot)
{
  __shared__ float T[32][33];
  const int idx = blockIdx.x;
  if (idx < 1024) {
    tr_tile(wq, wqkvt, 1024, idx & 31, idx >> 5, T);
  } else if (idx < 1280) {
    const int i = idx - 1024;
    tr_tile(wk, wqkvt + 1024 * 1024, 256, i & 7, i >> 3, T);
  } else if (idx < 1536) {
    const int i = idx - 1280;
    tr_tile(wv, wqkvt + 1280 * 1024, 256, i & 7, i >> 3, T);
  } else if (idx < 2560) {
    const int i = idx - 1536;
    tr_tile(wo, wot, 1024, i & 31, i >> 5, T);
  } else {
    const int i = idx - 2560;
#pragma unroll
    for (int j = 0; j < 4; ++j) {
      const int id = i * 1024 + (int)threadIdx.x + j * 256;
      const float4 v = ((const float4*)x)[id];
      ushort4 o;
      o.x = ftob(v.x); o.y = ftob(v.y); o.z = ftob(v.z); o.w = ftob(v.w);
      ((ushort4*)xb)[id] = o;
    }
  }
}

// ---------------------------------------------------------------------------
// 64x128 GEMM core, 2-phase: BK=64 (two BK=32 panels), double-buffered LDS,
// global_load_lds w16, ONE barrier per K-step.
// ---------------------------------------------------------------------------
#define G64DB_STAGE(A_, B_, bo_, k0_)                                           \
  do {                                                                          \
    const int r = tid >> 2, o8 = (tid & 3) * 8;                                 \
    gll16(&A_[(size_t)(bm + r) * 1024 + (k0_) + o8], &sm[(bo_) + tid * 8]);     \
    gll16(&A_[(size_t)(bm + r) * 1024 + (k0_) + 32 + o8],                       \
          &sm[(bo_) + 2048 + tid * 8]);                                         \
    gll16(&B_[(size_t)(bn0 * 128 + r) * 1024 + (k0_) + o8],                     \
          &sm[(bo_) + 4096 + tid * 8]);                                         \
    gll16(&B_[(size_t)(bn0 * 128 + r + 64) * 1024 + (k0_) + o8],                \
          &sm[(bo_) + 6144 + tid * 8]);                                         \
    gll16(&B_[(size_t)(bn0 * 128 + r) * 1024 + (k0_) + 32 + o8],                \
          &sm[(bo_) + 8192 + tid * 8]);                                         \
    gll16(&B_[(size_t)(bn0 * 128 + r + 64) * 1024 + (k0_) + 32 + o8],           \
          &sm[(bo_) + 10240 + tid * 8]);                                        \
  } while (0)

#define G64DB_KLOOP(A_, B_)                                                     \
  G64DB_STAGE(A_, B_, 0, 0);                                                    \
  __syncthreads();                                                              \
  for (int s = 0; s < 16; ++s) {                                                \
    const int bo = (s & 1) * 12288;                                             \
    if (s < 15) G64DB_STAGE(A_, B_, bo ^ 12288, (s + 1) * 64);                  \
    bf16_8 af[2][2], bf[2][4];                                                  \
    _Pragma("unroll")                                                           \
    for (int ks = 0; ks < 2; ++ks) {                                            \
      _Pragma("unroll")                                                         \
      for (int mt = 0; mt < 2; ++mt)                                            \
        af[ks][mt] = *(const bf16_8*)&sm[bo + ks * 2048 +                       \
                                         (mh + mt * 16 + l16) * 32 + quad * 8]; \
      _Pragma("unroll")                                                         \
      for (int nt = 0; nt < 4; ++nt)                                            \
        bf[ks][nt] = *(const bf16_8*)&sm[bo + 4096 + ks * 4096 +                \
                                         (nh + nt * 16 + l16) * 32 + quad * 8]; \
    }                                                                           \
    _Pragma("unroll")                                                           \
    for (int ks = 0; ks < 2; ++ks)                                              \
      _Pragma("unroll")                                                         \
      for (int mt = 0; mt < 2; ++mt)                                            \
        _Pragma("unroll")                                                       \
        for (int nt = 0; nt < 4; ++nt)                                          \
          acc[mt][nt] = __builtin_amdgcn_mfma_f32_16x16x32_bf16(                \
              af[ks][mt], bf[ks][nt], acc[mt][nt], 0, 0, 0);                    \
    __syncthreads();                                                            \
  }

// ---------------------------------------------------------------------------
// Fused QKV GEMM: [4096][1536] = xb @ wqkvt^T. BM=64, BN=128, grid (12,64).
// Epilogue: bn0 0..7 Q rope+scale -> qb; 8..9 K rope -> Kimg (PERMUTED rows,
// swizzled); 10..11 V -> LDS transpose -> Vimg (swizzled, b128 stores).
// ---------------------------------------------------------------------------
__global__ __launch_bounds__(256, 3) void gemm_qkv(
    const unsigned short* __restrict__ A, const unsigned short* __restrict__ Bt,
    unsigned short* __restrict__ qb, unsigned short* __restrict__ Kimg,
    unsigned short* __restrict__ Vimg,
    const float* __restrict__ cosT, const float* __restrict__ sinT)
{
  __shared__ unsigned short sm[24576];  // 2x12288 staging; V-epilogue reuses [0,9216)
  const int bm = blockIdx.y * 64, bn0 = blockIdx.x;
  const int tid = threadIdx.x;
  const int w = tid >> 6, lane = tid & 63, l16 = lane & 15, quad = lane >> 4;
  const int mh = (w & 1) * 32, nh = (w >> 1) * 64;

  f32_4 acc[2][4];
#pragma unroll
  for (int mt = 0; mt < 2; ++mt)
#pragma unroll
    for (int nt = 0; nt < 4; ++nt) acc[mt][nt] = (f32_4){0.f, 0.f, 0.f, 0.f};

  G64DB_KLOOP(A, Bt);

  const int colbase = bn0 * 128;
  if (colbase < 1024) {            // ---- Q: rope + scale ----
#pragma unroll
    for (int mt = 0; mt < 2; ++mt)
#pragma unroll
      for (int r = 0; r < 4; ++r) {
        const int row = bm + mh + mt * 16 + quad * 4 + r;
        const int s = row & (S_LEN - 1);
#pragma unroll
        for (int nt = 0; nt < 4; ++nt) {
          const int col = colbase + nh + nt * 16 + l16;
          float val = acc[mt][nt][r];
          const float pv = __shfl_xor(val, 1);
          const int fi = (col & 63) >> 1;
          const float cc = cosT[s * 32 + fi], ss = sinT[s * 32 + fi];
          val = (l16 & 1) ? fmaf(pv, ss, val * cc) : fmaf(val, cc, -(pv * ss));
          qb[(size_t)row * 1024 + col] = ftob(val * QSCALE);
        }
      }
  } else if (colbase < 1280) {     // ---- K: rope -> permuted+swizzled image ----
#pragma unroll
    for (int mt = 0; mt < 2; ++mt)
#pragma unroll
      for (int r = 0; r < 4; ++r) {
        const int row = bm + mh + mt * 16 + quad * 4 + r;
        const int s = row & (S_LEN - 1), bi = row >> 11;
        const int tile = s >> 6, key = s & 63;
        // permuted image row: row mt*16+q*4+rr holds key 32*(mt>>1)+q*8+(mt&1)*4+rr
        const int kk = key & 31, jj = kk & 7;
        const int rowp = ((key >> 5) << 5) + ((jj >> 2) << 4) + ((kk >> 3) << 2) + (jj & 3);
#pragma unroll
        for (int nt = 0; nt < 4; ++nt) {
          const int col = colbase + nh + nt * 16 + l16;
          float val = acc[mt][nt][r];
          const float pv = __shfl_xor(val, 1);
          const int fi = (col & 63) >> 1;
          const float cc = cosT[s * 32 + fi], ss = sinT[s * 32 + fi];
          val = (l16 & 1) ? fmaf(pv, ss, val * cc) : fmaf(val, cc, -(pv * ss));
          const int gcol = col - 1024, g = gcol >> 6, d = gcol & 63;
          Kimg[(size_t)((bi * 4 + g) * 32 + tile) * 4096 + rowp * 64 +
               (((d >> 3) ^ (rowp & 7)) * 8) + (d & 7)] = ftob(val);
        }
      }
  } else {                         // ---- V: LDS transpose -> swizzled image ----
    const int bi = bm >> 11, t0 = (bm & 2047) >> 6;
    const int gp = (bn0 - 10) * 2;
    __syncthreads();               // staging reads done before sm reuse
    {
      // wave w covers group gp + (w>>1), keys mh..mh+31, d 0..63
      unsigned short* Ts = sm + (w >> 1) * 4608;   // [64 d][72]
#pragma unroll
      for (int mt = 0; mt < 2; ++mt)
#pragma unroll
        for (int nt = 0; nt < 4; ++nt) {
          const int keyb = mh + mt * 16 + quad * 4;  // 4 consecutive keys
          const int d = nt * 16 + l16;
          ushort4 pk;
#pragma unroll
          for (int r = 0; r < 4; ++r) ((unsigned short*)&pk)[r] = ftob(acc[mt][nt][r]);
          *(ushort4*)&Ts[d * 72 + keyb] = pk;
        }
    }
    __syncthreads();
#pragma unroll
    for (int it = 0; it < 4; ++it) {
      const int c = tid + it * 256;              // 1024 chunks: 2 imgs x 512
      const int img = c >> 9, cc = c & 511;
      const int d = cc >> 3, ch = cc & 7;
      const uint4 v = *(const uint4*)&sm[img * 4608 + d * 72 + ch * 8];
      *(uint4*)&Vimg[(size_t)((bi * 4 + gp + img) * 32 + t0) * 4096 + d * 64 +
                     ((ch ^ (d & 7)) * 8)] = v;
    }
  }
}

// ---------------------------------------------------------------------------
// Output GEMM: out[4096][1024] fp32 = attn @ wot^T. BM=64, BN=128, grid (8,64).
// ---------------------------------------------------------------------------
__global__ __launch_bounds__(256, 2) void gemm_wo(
    const unsigned short* __restrict__ A, const unsigned short* __restrict__ Bt,
    float* __restrict__ C)
{
  __shared__ unsigned short sm[24576];
  const int bm = blockIdx.y * 64, bn0 = blockIdx.x;
  const int tid = threadIdx.x;
  const int w = tid >> 6, lane = tid & 63, l16 = lane & 15, quad = lane >> 4;
  const int mh = (w & 1) * 32, nh = (w >> 1) * 64;

  f32_4 acc[2][4];
#pragma unroll
  for (int mt = 0; mt < 2; ++mt)
#pragma unroll
    for (int nt = 0; nt < 4; ++nt) acc[mt][nt] = (f32_4){0.f, 0.f, 0.f, 0.f};

  G64DB_KLOOP(A, Bt);

#pragma unroll
  for (int mt = 0; mt < 2; ++mt)
#pragma unroll
    for (int r = 0; r < 4; ++r) {
      const int row = bm + mh + mt * 16 + quad * 4 + r;
#pragma unroll
      for (int nt = 0; nt < 4; ++nt)
        C[(size_t)row * 1024 + bn0 * 128 + nh + nt * 16 + l16] = acc[mt][nt][r];
    }
}

// ---------------------------------------------------------------------------
// Flash attention v11: Ps-free. Kimg's permuted rows make the packed QK^T
// output ALREADY lane-local in PV B-frag order -> the P LDS roundtrip (8 KB
// port traffic + 12 LDS ops/tile) vanishes. Freed 32 KB funds double-buffered
// K/V staging: ONE barrier per step, DMA in flight across the whole compute
// phase. l computed via ones-MFMA row-sum of the SAME bf16 P used for PV
// (exact convex combination; removes 32 VALU adds/tile + finalize shuffles).
// 512 threads = 4 heads x 2 key-parities; parity partials combine linearly.
// grid 512 (2/CU, 66 KB LDS); gb = id&7 pins (b,g) to one XCD.
// O aliases qb: reads at entry, writes same region at exit; disjoint across
// blocks; within-block the combine barrier orders reads before writes.
// ---------------------------------------------------------------------------
__global__ __launch_bounds__(512, 4) void flash_attn_v11(
    const unsigned short* __restrict__ Q, const unsigned short* __restrict__ Kimg,
    const unsigned short* __restrict__ Vimg, unsigned short* __restrict__ O)
{
  __shared__ unsigned short Ks[2][8192];       // [buf][par*4096 + row*64+..]
  __shared__ unsigned short Vs[2][8192];
  __shared__ float lbuf[4][2][64];
  const int id = blockIdx.x;
  const int gb = id & 7;                       // b*4+g -> XCD pin
  const int g = gb & 3, b = gb >> 2;
  const int j = id >> 3;                       // 0..63
  const int qc = (j < 32) ? (63 - j) : (j - 32);   // CU pair sums to 33 tiles
  const int tid = threadIdx.x;
  const int w = tid >> 6, lane = tid & 63, l16 = lane & 15, quad = lane >> 4;
  const int hw = w & 3, par = w >> 2;          // head-in-group, key parity
  const int h = g * 4 + hw;
  const int qbase = qc * 32;
  const int swz = l16 & 7;

  // ones A-frag for the l row-sum MFMA
  union { bf16_8 v; unsigned short u[8]; } ones;
#pragma unroll
  for (int i = 0; i < 8; ++i) ones.u[i] = 0x3f80;

  // Q B-frags (register-resident): n = q = l16 (+16*qf), k = d = quad*8+j
  bf16_8 bq[2][2];
#pragma unroll
  for (int qf = 0; qf < 2; ++qf) {
    const unsigned short* qp =
        Q + ((size_t)(b * S_LEN + qbase + qf * 16 + l16)) * 1024 + h * 64;
    bq[qf][0] = *(const bf16_8*)(qp + quad * 8);
    bq[qf][1] = *(const bf16_8*)(qp + 32 + quad * 8);
  }

  f32_4 acc[2][4], acc_l[2];
#pragma unroll
  for (int qf = 0; qf < 2; ++qf) {
    acc_l[qf] = (f32_4){0.f, 0.f, 0.f, 0.f};
#pragma unroll
    for (int mt = 0; mt < 4; ++mt) acc[qf][mt] = (f32_4){0.f, 0.f, 0.f, 0.f};
  }

  const unsigned short* kim = Kimg + (size_t)(gb * 32) * 4096;
  const unsigned short* vim = Vimg + (size_t)(gb * 32) * 4096;
  const int ntiles = (qc >> 1) + 1;
  const int steps = (ntiles + 1) >> 1;
  const int hq = (qc & 1) * 32;                // q offset within diag tile

  // prologue: stage tiles 0,1 into buf 0 (32 KB; 4 gll16/thread)
  {
    gll16(kim + tid * 8, &Ks[0][tid * 8]);
    gll16(kim + (tid + 512) * 8, &Ks[0][(tid + 512) * 8]);
    gll16(vim + tid * 8, &Vs[0][tid * 8]);
    gll16(vim + (tid + 512) * 8, &Vs[0][(tid + 512) * 8]);
  }
  for (int s = 0; s < steps; ++s) {
    const int c = s & 1;
    __syncthreads();                   // own vmcnt drained -> buf c ready;
                                       // prev readers of buf c^1 also done
    if (s + 1 < steps) {
      const unsigned short* kp = kim + (size_t)(s + 1) * 8192;
      const unsigned short* vp = vim + (size_t)(s + 1) * 8192;
      gll16(kp + tid * 8, &Ks[c ^ 1][tid * 8]);
      gll16(kp + (tid + 512) * 8, &Ks[c ^ 1][(tid + 512) * 8]);
      gll16(vp + tid * 8, &Vs[c ^ 1][tid * 8]);
      gll16(vp + (tid + 512) * 8, &Vs[c ^ 1][(tid + 512) * 8]);
    }

    const int tile = 2 * s + par;
    if (tile < ntiles) {
      const bool diag = (tile == ntiles - 1);
      const unsigned short* ks = &Ks[c][par * 4096];
      const unsigned short* vs = &Vs[c][par * 4096];
      // ---- S^T = K Q^T; p = exp2(s); pack DIRECTLY into PV B-frags ----
      union { bf16_8 v; unsigned int wd[4]; } pf[2][2];
#pragma unroll
      for (int mt = 0; mt < 4; ++mt) {
        const int krow = (mt * 16 + l16) * 64;
        const bf16_8 kf0 = *(const bf16_8*)&ks[krow + (quad ^ swz) * 8];
        const bf16_8 kf1 = *(const bf16_8*)&ks[krow + ((4 + quad) ^ swz) * 8];
#pragma unroll
        for (int qf = 0; qf < 2; ++qf) {
          f32_4 z = (f32_4){0.f, 0.f, 0.f, 0.f};
          __builtin_amdgcn_s_setprio(1);
          z = __builtin_amdgcn_mfma_f32_16x16x32_bf16(kf0, bq[qf][0], z, 0, 0, 0);
          z = __builtin_amdgcn_mfma_f32_16x16x32_bf16(kf1, bq[qf][1], z, 0, 0, 0);
          __builtin_amdgcn_s_setprio(0);
          float pv[4];
#pragma unroll
          for (int r = 0; r < 4; ++r) {
            float p = __builtin_amdgcn_exp2f(z[r]);
            if (diag) {
              // actual key of z[mt] reg r (permuted rows):
              const int keyl = ((mt >> 1) << 5) + quad * 8 + ((mt & 1) << 2) + r;
              const int ql = hq + qf * 16 + l16;
              p = (keyl > ql) ? 0.f : p;
            }
            pv[r] = p;
          }
          pf[qf][mt >> 1].wd[(mt & 1) * 2 + 0] =
              (unsigned int)ftob(pv[0]) | ((unsigned int)ftob(pv[1]) << 16);
          pf[qf][mt >> 1].wd[(mt & 1) * 2 + 1] =
              (unsigned int)ftob(pv[2]) | ((unsigned int)ftob(pv[3]) << 16);
        }
      }
      // ---- l via ones-MFMA row-sum (all quads/regs hold the full sum) ----
#pragma unroll
      for (int qf = 0; qf < 2; ++qf) {
        acc_l[qf] = __builtin_amdgcn_mfma_f32_16x16x32_bf16(ones.v, pf[qf][0].v, acc_l[qf], 0, 0, 0);
        acc_l[qf] = __builtin_amdgcn_mfma_f32_16x16x32_bf16(ones.v, pf[qf][1].v, acc_l[qf], 0, 0, 0);
      }
      // ---- O^T += V^T @ P^T (pf straight from registers) ----
      __builtin_amdgcn_s_setprio(1);
#pragma unroll
      for (int mt = 0; mt < 4; ++mt) {
        const int vrow = (mt * 16 + l16) * 64;
        const bf16_8 vf0 = *(const bf16_8*)&vs[vrow + (quad ^ swz) * 8];
        const bf16_8 vf1 = *(const bf16_8*)&vs[vrow + ((4 + quad) ^ swz) * 8];
#pragma unroll
        for (int qf = 0; qf < 2; ++qf) {
          acc[qf][mt] = __builtin_amdgcn_mfma_f32_16x16x32_bf16(vf0, pf[qf][0].v, acc[qf][mt], 0, 0, 0);
          acc[qf][mt] = __builtin_amdgcn_mfma_f32_16x16x32_bf16(vf1, pf[qf][1].v, acc[qf][mt], 0, 0, 0);
        }
      }
      __builtin_amdgcn_s_setprio(0);
    }
  }

  // ---- combine parity partials (linear; no running max) ----
  __syncthreads();                             // all compute done; Ks reusable
  float* cb = (float*)&Ks[0][0];               // 4 heads x 2048 floats = 32 KB
  if (par == 1) {
    float* dst = cb + hw * 2048;
#pragma unroll
    for (int qf = 0; qf < 2; ++qf)
#pragma unroll
      for (int mt = 0; mt < 4; ++mt)
#pragma unroll
        for (int r = 0; r < 4; ++r)
          dst[(qf * 16 + mt * 4 + r) * 64 + lane] = acc[qf][mt][r];
    lbuf[hw][0][lane] = acc_l[0][0];
    lbuf[hw][1][lane] = acc_l[1][0];
  }
  __syncthreads();
  if (par == 0) {
    const float* src = cb + hw * 2048;
#pragma unroll
    for (int qf = 0; qf < 2; ++qf)
#pragma unroll
      for (int mt = 0; mt < 4; ++mt)
#pragma unroll
        for (int r = 0; r < 4; ++r)
          acc[qf][mt][r] += src[(qf * 16 + mt * 4 + r) * 64 + lane];

    // ---- finalize: l is already the full row sum per lane; write O^T ----
#pragma unroll
    for (int qf = 0; qf < 2; ++qf) {
      const float l = acc_l[qf][0] + lbuf[hw][qf][lane];
      const float inv = 1.f / l;
      unsigned short* op =
          O + ((size_t)(b * S_LEN + qbase + qf * 16 + l16)) * 1024 + h * 64;
#pragma unroll
      for (int mt = 0; mt < 4; ++mt) {
        ushort4 ov;
#pragma unroll
        for (int r = 0; r < 4; ++r) ((unsigned short*)&ov)[r] = ftob(acc[qf][mt][r] * inv);
        *(ushort4*)&op[mt * 16 + quad * 4] = ov;
      }
    }
  }
}

// ---------------------------------------------------------------------------
extern "C" void kernel_launch(void* const* d_in, const int* in_sizes, int n_in,
                              void* d_out, int out_size, void* d_ws, size_t ws_size,
                              hipStream_t stream)
{
  const float* x    = (const float*)d_in[0];
  const float* cosT = (const float*)d_in[1];
  const float* sinT = (const float*)d_in[2];
  const float* wq   = (const float*)d_in[4];
  const float* wk   = (const float*)d_in[5];
  const float* wv   = (const float*)d_in[6];
  const float* wo   = (const float*)d_in[7];
  float* out = (float*)d_out;

  char* ws = (char*)d_ws;
  const size_t MB = 1024 * 1024;
  unsigned short* xb    = (unsigned short*)(ws);             // 8 MB
  unsigned short* qb    = (unsigned short*)(ws + 8 * MB);    // 8 MB [4096][1024]
  unsigned short* wqkvt = (unsigned short*)(ws + 16 * MB);   // 3 MB [1536][1024]
  unsigned short* Kimg  = (unsigned short*)(ws + 19 * MB);   // 2 MB (permuted+swizzled)
  unsigned short* Vimg  = (unsigned short*)(ws + 21 * MB);   // 2 MB (swizzled)
  unsigned short* wot   = (unsigned short*)(ws + 23 * MB);   // 2 MB [1024][1024]
  // total ws use: 25 MB

  prep<<<3584, 256, 0, stream>>>(x, wq, wk, wv, wo, xb, wqkvt, wot);
  gemm_qkv<<<dim3(12, 64), 256, 0, stream>>>(xb, wqkvt, qb, Kimg, Vimg, cosT, sinT);
  flash_attn_v11<<<512, 512, 0, stream>>>(qb, Kimg, Vimg, qb);
  gemm_wo<<<dim3(8, 64), 256, 0, stream>>>(qb, wot, out);
}

// Round 7
// 165.612 us; speedup vs baseline: 1.0084x; 1.0084x over previous
//
#include <hip/hip_runtime.h>
#include <math.h>

#define S_LEN 2048
#define B_SZ 2

typedef __bf16 bf16_8 __attribute__((ext_vector_type(8)));
typedef float  f32_4  __attribute__((ext_vector_type(4)));

__device__ __forceinline__ unsigned short ftob(float f) {
  union { __bf16 h; unsigned short u; } cv;
  cv.h = (__bf16)f;              // fptrunc -> RNE
  return cv.u;
}

// async global->LDS, 16B per lane. LDS dest must be wave-uniform base + lane*16.
__device__ __forceinline__ void gll16(const unsigned short* g, unsigned short* l) {
  __builtin_amdgcn_global_load_lds(
      (const __attribute__((address_space(1))) unsigned int*)g,
      (__attribute__((address_space(3))) unsigned int*)l, 16, 0, 0);
}

// fold 1/sqrt(64) * log2(e) into Q at projection -> softmax in exp2 domain
#define QSCALE (0.125f * 1.44269504f)

// K/V tile images: dense 64x64 bf16 (4096 shorts = 8 KB), 16B-chunk XOR
// swizzle: element (row, col) at row*64 + ((col>>3) ^ (row&7))*8 + (col&7).
// V image rows = d, cols = key (natural order).
// K image rows are PERMUTED keys: image row mt*16 + q*4 + r holds key
// 32*(mt>>1) + q*8 + (mt&1)*4 + r. With this ordering the QK^T C-layout
// (keys at quad*4+r per z[mt]) packs DIRECTLY into the PV B-frag layout
// (keys at quad*8+j) lane-locally -> no P LDS roundtrip at all.

// ---------------------------------------------------------------------------
// 32x32 transpose+convert tile helper: W[K=1024][N] fp32 -> Wt[N][1024] bf16.
// ---------------------------------------------------------------------------
__device__ __forceinline__ void tr_tile(const float* __restrict__ W,
                                        unsigned short* __restrict__ Wt,
                                        int N, int bx, int by, float (*T)[33])
{
  const int k0 = by * 32, n0 = bx * 32;
  const int r = threadIdx.x >> 3, c4 = (threadIdx.x & 7) * 4;
  const float4 v = *(const float4*)&W[(size_t)(k0 + r) * N + n0 + c4];
  T[r][c4 + 0] = v.x; T[r][c4 + 1] = v.y;
  T[r][c4 + 2] = v.z; T[r][c4 + 3] = v.w;
  __syncthreads();
  ushort4 o;
  o.x = ftob(T[c4 + 0][r]); o.y = ftob(T[c4 + 1][r]);
  o.z = ftob(T[c4 + 2][r]); o.w = ftob(T[c4 + 3][r]);
  *(ushort4*)&Wt[(size_t)(n0 + r) * 1024 + k0 + c4] = o;
}

// ---------------------------------------------------------------------------
// prep: [0,1024) wq->wqkvt | [1024,1280) wk | [1280,1536) wv |
//       [1536,2560) wo->wot | [2560,3584) x fp32->bf16
// ---------------------------------------------------------------------------
__global__ __launch_bounds__(256) void prep(
    const float* __restrict__ x, const float* __restrict__ wq,
    const float* __restrict__ wk, const float* __restrict__ wv,
    const float* __restrict__ wo,
    unsigned short* __restrict__ xb, unsigned short* __restrict__ wqkvt,
    unsigned short* __restrict__ wot)
{
  __shared__ float T[32][33];
  const int idx = blockIdx.x;
  if (idx < 1024) {
    tr_tile(wq, wqkvt, 1024, idx & 31, idx >> 5, T);
  } else if (idx < 1280) {
    const int i = idx - 1024;
    tr_tile(wk, wqkvt + 1024 * 1024, 256, i & 7, i >> 3, T);
  } else if (idx < 1536) {
    const int i = idx - 1280;
    tr_tile(wv, wqkvt + 1280 * 1024, 256, i & 7, i >> 3, T);
  } else if (idx < 2560) {
    const int i = idx - 1536;
    tr_tile(wo, wot, 1024, i & 31, i >> 5, T);
  } else {
    const int i = idx - 2560;
#pragma unroll
    for (int j = 0; j < 4; ++j) {
      const int id = i * 1024 + (int)threadIdx.x + j * 256;
      const float4 v = ((const float4*)x)[id];
      ushort4 o;
      o.x = ftob(v.x); o.y = ftob(v.y); o.z = ftob(v.z); o.w = ftob(v.w);
      ((ushort4*)xb)[id] = o;
    }
  }
}

// ---------------------------------------------------------------------------
// 64x128 GEMM core, 2-phase: BK=64 (two BK=32 panels), double-buffered LDS,
// global_load_lds w16, ONE barrier per K-step.
// ---------------------------------------------------------------------------
#define G64DB_STAGE(A_, B_, bo_, k0_)                                           \
  do {                                                                          \
    const int r = tid >> 2, o8 = (tid & 3) * 8;                                 \
    gll16(&A_[(size_t)(bm + r) * 1024 + (k0_) + o8], &sm[(bo_) + tid * 8]);     \
    gll16(&A_[(size_t)(bm + r) * 1024 + (k0_) + 32 + o8],                       \
          &sm[(bo_) + 2048 + tid * 8]);                                         \
    gll16(&B_[(size_t)(bn0 * 128 + r) * 1024 + (k0_) + o8],                     \
          &sm[(bo_) + 4096 + tid * 8]);                                         \
    gll16(&B_[(size_t)(bn0 * 128 + r + 64) * 1024 + (k0_) + o8],                \
          &sm[(bo_) + 6144 + tid * 8]);                                         \
    gll16(&B_[(size_t)(bn0 * 128 + r) * 1024 + (k0_) + 32 + o8],                \
          &sm[(bo_) + 8192 + tid * 8]);                                         \
    gll16(&B_[(size_t)(bn0 * 128 + r + 64) * 1024 + (k0_) + 32 + o8],           \
          &sm[(bo_) + 10240 + tid * 8]);                                        \
  } while (0)

#define G64DB_KLOOP(A_, B_)                                                     \
  G64DB_STAGE(A_, B_, 0, 0);                                                    \
  __syncthreads();                                                              \
  for (int s = 0; s < 16; ++s) {                                                \
    const int bo = (s & 1) * 12288;                                             \
    if (s < 15) G64DB_STAGE(A_, B_, bo ^ 12288, (s + 1) * 64);                  \
    bf16_8 af[2][2], bf[2][4];                                                  \
    _Pragma("unroll")                                                           \
    for (int ks = 0; ks < 2; ++ks) {                                            \
      _Pragma("unroll")                                                         \
      for (int mt = 0; mt < 2; ++mt)                                            \
        af[ks][mt] = *(const bf16_8*)&sm[bo + ks * 2048 +                       \
                                         (mh + mt * 16 + l16) * 32 + quad * 8]; \
      _Pragma("unroll")                                                         \
      for (int nt = 0; nt < 4; ++nt)                                            \
        bf[ks][nt] = *(const bf16_8*)&sm[bo + 4096 + ks * 4096 +                \
                                         (nh + nt * 16 + l16) * 32 + quad * 8]; \
    }                                                                           \
    _Pragma("unroll")                                                           \
    for (int ks = 0; ks < 2; ++ks)                                              \
      _Pragma("unroll")                                                         \
      for (int mt = 0; mt < 2; ++mt)                                            \
        _Pragma("unroll")                                                       \
        for (int nt = 0; nt < 4; ++nt)                                          \
          acc[mt][nt] = __builtin_amdgcn_mfma_f32_16x16x32_bf16(                \
              af[ks][mt], bf[ks][nt], acc[mt][nt], 0, 0, 0);                    \
    __syncthreads();                                                            \
  }

// ---------------------------------------------------------------------------
// Fused QKV GEMM: [4096][1536] = xb @ wqkvt^T. BM=64, BN=128, grid (12,64).
// Epilogue: bn0 0..7 Q rope+scale -> qb; 8..9 K rope -> Kimg (PERMUTED rows,
// swizzled); 10..11 V -> LDS transpose -> Vimg (swizzled, b128 stores).
// ---------------------------------------------------------------------------
__global__ __launch_bounds__(256, 3) void gemm_qkv(
    const unsigned short* __restrict__ A, const unsigned short* __restrict__ Bt,
    unsigned short* __restrict__ qb, unsigned short* __restrict__ Kimg,
    unsigned short* __restrict__ Vimg,
    const float* __restrict__ cosT, const float* __restrict__ sinT)
{
  __shared__ unsigned short sm[24576];  // 2x12288 staging; V-epilogue reuses [0,9216)
  const int bm = blockIdx.y * 64, bn0 = blockIdx.x;
  const int tid = threadIdx.x;
  const int w = tid >> 6, lane = tid & 63, l16 = lane & 15, quad = lane >> 4;
  const int mh = (w & 1) * 32, nh = (w >> 1) * 64;

  f32_4 acc[2][4];
#pragma unroll
  for (int mt = 0; mt < 2; ++mt)
#pragma unroll
    for (int nt = 0; nt < 4; ++nt) acc[mt][nt] = (f32_4){0.f, 0.f, 0.f, 0.f};

  G64DB_KLOOP(A, Bt);

  const int colbase = bn0 * 128;
  if (colbase < 1024) {            // ---- Q: rope + scale ----
#pragma unroll
    for (int mt = 0; mt < 2; ++mt)
#pragma unroll
      for (int r = 0; r < 4; ++r) {
        const int row = bm + mh + mt * 16 + quad * 4 + r;
        const int s = row & (S_LEN - 1);
#pragma unroll
        for (int nt = 0; nt < 4; ++nt) {
          const int col = colbase + nh + nt * 16 + l16;
          float val = acc[mt][nt][r];
          const float pv = __shfl_xor(val, 1);
          const int fi = (col & 63) >> 1;
          const float cc = cosT[s * 32 + fi], ss = sinT[s * 32 + fi];
          val = (l16 & 1) ? fmaf(pv, ss, val * cc) : fmaf(val, cc, -(pv * ss));
          qb[(size_t)row * 1024 + col] = ftob(val * QSCALE);
        }
      }
  } else if (colbase < 1280) {     // ---- K: rope -> permuted+swizzled image ----
#pragma unroll
    for (int mt = 0; mt < 2; ++mt)
#pragma unroll
      for (int r = 0; r < 4; ++r) {
        const int row = bm + mh + mt * 16 + quad * 4 + r;
        const int s = row & (S_LEN - 1), bi = row >> 11;
        const int tile = s >> 6, key = s & 63;
        // permuted image row: row mt*16+q*4+rr holds key 32*(mt>>1)+q*8+(mt&1)*4+rr
        const int kk = key & 31, jj = kk & 7;
        const int rowp = ((key >> 5) << 5) + ((jj >> 2) << 4) + ((kk >> 3) << 2) + (jj & 3);
#pragma unroll
        for (int nt = 0; nt < 4; ++nt) {
          const int col = colbase + nh + nt * 16 + l16;
          float val = acc[mt][nt][r];
          const float pv = __shfl_xor(val, 1);
          const int fi = (col & 63) >> 1;
          const float cc = cosT[s * 32 + fi], ss = sinT[s * 32 + fi];
          val = (l16 & 1) ? fmaf(pv, ss, val * cc) : fmaf(val, cc, -(pv * ss));
          const int gcol = col - 1024, g = gcol >> 6, d = gcol & 63;
          Kimg[(size_t)((bi * 4 + g) * 32 + tile) * 4096 + rowp * 64 +
               (((d >> 3) ^ (rowp & 7)) * 8) + (d & 7)] = ftob(val);
        }
      }
  } else {                         // ---- V: LDS transpose -> swizzled image ----
    const int bi = bm >> 11, t0 = (bm & 2047) >> 6;
    const int gp = (bn0 - 10) * 2;
    __syncthreads();               // staging reads done before sm reuse
    {
      // wave w covers group gp + (w>>1), keys mh..mh+31, d 0..63
      unsigned short* Ts = sm + (w >> 1) * 4608;   // [64 d][72]
#pragma unroll
      for (int mt = 0; mt < 2; ++mt)
#pragma unroll
        for (int nt = 0; nt < 4; ++nt) {
          const int keyb = mh + mt * 16 + quad * 4;  // 4 consecutive keys
          const int d = nt * 16 + l16;
          ushort4 pk;
#pragma unroll
          for (int r = 0; r < 4; ++r) ((unsigned short*)&pk)[r] = ftob(acc[mt][nt][r]);
          *(ushort4*)&Ts[d * 72 + keyb] = pk;
        }
    }
    __syncthreads();
#pragma unroll
    for (int it = 0; it < 4; ++it) {
      const int c = tid + it * 256;              // 1024 chunks: 2 imgs x 512
      const int img = c >> 9, cc = c & 511;
      const int d = cc >> 3, ch = cc & 7;
      const uint4 v = *(const uint4*)&sm[img * 4608 + d * 72 + ch * 8];
      *(uint4*)&Vimg[(size_t)((bi * 4 + gp + img) * 32 + t0) * 4096 + d * 64 +
                     ((ch ^ (d & 7)) * 8)] = v;
    }
  }
}

// ---------------------------------------------------------------------------
// Output GEMM: out[4096][1024] fp32 = attn @ wot^T. BM=64, BN=128, grid (8,64).
// ---------------------------------------------------------------------------
__global__ __launch_bounds__(256, 2) void gemm_wo(
    const unsigned short* __restrict__ A, const unsigned short* __restrict__ Bt,
    float* __restrict__ C)
{
  __shared__ unsigned short sm[24576];
  const int bm = blockIdx.y * 64, bn0 = blockIdx.x;
  const int tid = threadIdx.x;
  const int w = tid >> 6, lane = tid & 63, l16 = lane & 15, quad = lane >> 4;
  const int mh = (w & 1) * 32, nh = (w >> 1) * 64;

  f32_4 acc[2][4];
#pragma unroll
  for (int mt = 0; mt < 2; ++mt)
#pragma unroll
    for (int nt = 0; nt < 4; ++nt) acc[mt][nt] = (f32_4){0.f, 0.f, 0.f, 0.f};

  G64DB_KLOOP(A, Bt);

#pragma unroll
  for (int mt = 0; mt < 2; ++mt)
#pragma unroll
    for (int r = 0; r < 4; ++r) {
      const int row = bm + mh + mt * 16 + quad * 4 + r;
#pragma unroll
      for (int nt = 0; nt < 4; ++nt)
        C[(size_t)row * 1024 + bn0 * 128 + nh + nt * 16 + l16] = acc[mt][nt][r];
    }
}

// ---------------------------------------------------------------------------
// Flash attention v12: 4-way key split in ONE 1024-thread block (16 waves =
// 4 heads x 4 key-quarters), one q-row-chunk per block. v9-v11 plateaued at
// 35-45us because wall time is set by the longest block's serial barrier
// steps at low waves/SIMD (VGPR caps the kernel at 16 waves/CU, so more
// waves is impossible; fewer+uniform serial steps is the only lever).
// Steps drop 16 -> max 8, uniform ~9/CU via two-phase snake: first 256
// blocks take qc=32..63 (ascending steps), queued 256 take qc=31..0
// (descending) -> earliest finishers pop the largest remaining rows.
// Per step: stage 4 tiles (64 KB, dbuf 128 KB -> 1 block/CU = the full
// 16-wave budget); wave (h,p) computes tile 4s+p. Quarter partials combine
// once per row via a 96 KB LDS exchange reusing the staging buffer (linear
// no-max combine, validated in v10/v11). Ps-free permuted-K packing (v11);
// VALU l_part (v10). gb = id&7 pins (b,g) to one XCD.
// O aliases qb: reads at entry, writes same region at exit; disjoint across
// blocks; within-block the combine barriers order reads before writes.
// ---------------------------------------------------------------------------
__global__ __launch_bounds__(1024, 4) void flash_attn_v12(
    const unsigned short* __restrict__ Q, const unsigned short* __restrict__ Kimg,
    const unsigned short* __restrict__ Vimg, unsigned short* __restrict__ O)
{
  __shared__ unsigned short KV[2][32768];  // [buf][ K 4x4096 | V 4x4096 ] shorts
  __shared__ float lbuf[12][2][64];
  const int id = blockIdx.x;
  const int gb = id & 7;                       // b*4+g -> XCD pin
  const int g = gb & 3, b = gb >> 2;
  const int i = id >> 3;                       // 0..63
  const int qc = (i < 32) ? (32 + i) : (63 - i);   // two-phase snake
  const int tid = threadIdx.x;
  const int w = tid >> 6, lane = tid & 63, l16 = lane & 15, quad = lane >> 4;
  const int hw = w & 3, p = w >> 2;            // head-in-group, key quarter
  const int h = g * 4 + hw;
  const int qbase = qc * 32;
  const int swz = l16 & 7;

  // Q B-frags (register-resident): n = q = l16 (+16*qf), k = d = quad*8+j
  bf16_8 bq[2][2];
#pragma unroll
  for (int qf = 0; qf < 2; ++qf) {
    const unsigned short* qp =
        Q + ((size_t)(b * S_LEN + qbase + qf * 16 + l16)) * 1024 + h * 64;
    bq[qf][0] = *(const bf16_8*)(qp + quad * 8);
    bq[qf][1] = *(const bf16_8*)(qp + 32 + quad * 8);
  }

  f32_4 acc[2][4];
  float l_part[2] = {0.f, 0.f};
#pragma unroll
  for (int qf = 0; qf < 2; ++qf)
#pragma unroll
    for (int mt = 0; mt < 4; ++mt) acc[qf][mt] = (f32_4){0.f, 0.f, 0.f, 0.f};

  const unsigned short* kim = Kimg + (size_t)(gb * 32) * 4096;
  const unsigned short* vim = Vimg + (size_t)(gb * 32) * 4096;
  const int ntiles = (qc >> 1) + 1;
  const int steps = (ntiles + 3) >> 2;
  const int hq = (qc & 1) * 32;                // q offset within diag tile

  // stage 4 tiles (32 KB K + 32 KB V) into buf c_; 4 gll16/thread.
  // staged range 4s..4s+3 <= 31 always (ceil(32/4)*4-1 = 31) -> in-bounds.
#define FA12_STAGE(s_, c_)                                                      \
  do {                                                                          \
    const unsigned short* kp = kim + (size_t)(s_) * 16384;                      \
    const unsigned short* vp = vim + (size_t)(s_) * 16384;                      \
    gll16(kp + tid * 8, &KV[c_][tid * 8]);                                      \
    gll16(kp + (tid + 1024) * 8, &KV[c_][(tid + 1024) * 8]);                    \
    gll16(vp + tid * 8, &KV[c_][16384 + tid * 8]);                              \
    gll16(vp + (tid + 1024) * 8, &KV[c_][16384 + (tid + 1024) * 8]);            \
  } while (0)

  FA12_STAGE(0, 0);
  for (int s = 0; s < steps; ++s) {
    const int c = s & 1;
    __syncthreads();                   // own vmcnt drained -> buf c ready;
                                       // prev readers of buf c^1 also done
    if (s + 1 < steps) FA12_STAGE(s + 1, c ^ 1);

    const int tile = 4 * s + p;
    if (tile < ntiles) {
      const bool diag = (tile == ntiles - 1);
      const unsigned short* ks = &KV[c][p * 4096];
      const unsigned short* vs = &KV[c][16384 + p * 4096];
      // ---- S^T = K Q^T; p = exp2(s); pack DIRECTLY into PV B-frags ----
      union { bf16_8 v; unsigned int wd[4]; } pf[2][2];
#pragma unroll
      for (int mt = 0; mt < 4; ++mt) {
        const int krow = (mt * 16 + l16) * 64;
        const bf16_8 kf0 = *(const bf16_8*)&ks[krow + (quad ^ swz) * 8];
        const bf16_8 kf1 = *(const bf16_8*)&ks[krow + ((4 + quad) ^ swz) * 8];
#pragma unroll
        for (int qf = 0; qf < 2; ++qf) {
          f32_4 z = (f32_4){0.f, 0.f, 0.f, 0.f};
          __builtin_amdgcn_s_setprio(1);
          z = __builtin_amdgcn_mfma_f32_16x16x32_bf16(kf0, bq[qf][0], z, 0, 0, 0);
          z = __builtin_amdgcn_mfma_f32_16x16x32_bf16(kf1, bq[qf][1], z, 0, 0, 0);
          __builtin_amdgcn_s_setprio(0);
          float pv[4];
#pragma unroll
          for (int r = 0; r < 4; ++r) {
            float pe = __builtin_amdgcn_exp2f(z[r]);
            if (diag) {
              // actual key of z[mt] reg r (permuted rows):
              const int keyl = ((mt >> 1) << 5) + quad * 8 + ((mt & 1) << 2) + r;
              const int ql = hq + qf * 16 + l16;
              pe = (keyl > ql) ? 0.f : pe;
            }
            l_part[qf] += pe;
            pv[r] = pe;
          }
          pf[qf][mt >> 1].wd[(mt & 1) * 2 + 0] =
              (unsigned int)ftob(pv[0]) | ((unsigned int)ftob(pv[1]) << 16);
          pf[qf][mt >> 1].wd[(mt & 1) * 2 + 1] =
              (unsigned int)ftob(pv[2]) | ((unsigned int)ftob(pv[3]) << 16);
        }
      }
      // ---- O^T += V^T @ P^T (pf straight from registers) ----
      __builtin_amdgcn_s_setprio(1);
#pragma unroll
      for (int mt = 0; mt < 4; ++mt) {
        const int vrow = (mt * 16 + l16) * 64;
        const bf16_8 vf0 = *(const bf16_8*)&vs[vrow + (quad ^ swz) * 8];
        const bf16_8 vf1 = *(const bf16_8*)&vs[vrow + ((4 + quad) ^ swz) * 8];
#pragma unroll
        for (int qf = 0; qf < 2; ++qf) {
          acc[qf][mt] = __builtin_amdgcn_mfma_f32_16x16x32_bf16(vf0, pf[qf][0].v, acc[qf][mt], 0, 0, 0);
          acc[qf][mt] = __builtin_amdgcn_mfma_f32_16x16x32_bf16(vf1, pf[qf][1].v, acc[qf][mt], 0, 0, 0);
        }
      }
      __builtin_amdgcn_s_setprio(0);
    }
  }

  // ---- combine quarter partials (linear; no running max) ----
  __syncthreads();                             // all compute done; KV reusable
  float* cb = (float*)&KV[0][0];               // 12 slots x 2048 f32 = 96 KB
  if (p != 0) {
    const int slot = (p - 1) * 4 + hw;
    float* dst = cb + slot * 2048;
#pragma unroll
    for (int qf = 0; qf < 2; ++qf)
#pragma unroll
      for (int mt = 0; mt < 4; ++mt)
#pragma unroll
        for (int r = 0; r < 4; ++r)
          dst[(qf * 16 + mt * 4 + r) * 64 + lane] = acc[qf][mt][r];
    lbuf[slot][0][lane] = l_part[0];
    lbuf[slot][1][lane] = l_part[1];
  }
  __syncthreads();
  if (p == 0) {
#pragma unroll
    for (int pp = 0; pp < 3; ++pp) {
      const int slot = pp * 4 + hw;
      const float* src = cb + slot * 2048;
#pragma unroll
      for (int qf = 0; qf < 2; ++qf)
#pragma unroll
        for (int mt = 0; mt < 4; ++mt)
#pragma unroll
          for (int r = 0; r < 4; ++r)
            acc[qf][mt][r] += src[(qf * 16 + mt * 4 + r) * 64 + lane];
      l_part[0] += lbuf[slot][0][lane];
      l_part[1] += lbuf[slot][1][lane];
    }

    // ---- finalize: l = sum over quads (keys partitioned by quad) ----
#pragma unroll
    for (int qf = 0; qf < 2; ++qf) {
      float l = l_part[qf];
      l += __shfl_xor(l, 16);
      l += __shfl_xor(l, 32);
      const float inv = 1.f / l;
      unsigned short* op =
          O + ((size_t)(b * S_LEN + qbase + qf * 16 + l16)) * 1024 + h * 64;
#pragma unroll
      for (int mt = 0; mt < 4; ++mt) {
        ushort4 ov;
#pragma unroll
        for (int r = 0; r < 4; ++r) ((unsigned short*)&ov)[r] = ftob(acc[qf][mt][r] * inv);
        *(ushort4*)&op[mt * 16 + quad * 4] = ov;
      }
    }
  }
}

// ---------------------------------------------------------------------------
extern "C" void kernel_launch(void* const* d_in, const int* in_sizes, int n_in,
                              void* d_out, int out_size, void* d_ws, size_t ws_size,
                              hipStream_t stream)
{
  const float* x    = (const float*)d_in[0];
  const float* cosT = (const float*)d_in[1];
  const float* sinT = (const float*)d_in[2];
  const float* wq   = (const float*)d_in[4];
  const float* wk   = (const float*)d_in[5];
  const float* wv   = (const float*)d_in[6];
  const float* wo   = (const float*)d_in[7];
  float* out = (float*)d_out;

  char* ws = (char*)d_ws;
  const size_t MB = 1024 * 1024;
  unsigned short* xb    = (unsigned short*)(ws);             // 8 MB
  unsigned short* qb    = (unsigned short*)(ws + 8 * MB);    // 8 MB [4096][1024]
  unsigned short* wqkvt = (unsigned short*)(ws + 16 * MB);   // 3 MB [1536][1024]
  unsigned short* Kimg  = (unsigned short*)(ws + 19 * MB);   // 2 MB (permuted+swizzled)
  unsigned short* Vimg  = (unsigned short*)(ws + 21 * MB);   // 2 MB (swizzled)
  unsigned short* wot   = (unsigned short*)(ws + 23 * MB);   // 2 MB [1024][1024]
  // total ws use: 25 MB

  prep<<<3584, 256, 0, stream>>>(x, wq, wk, wv, wo, xb, wqkvt, wot);
  gemm_qkv<<<dim3(12, 64), 256, 0, stream>>>(xb, wqkvt, qb, Kimg, Vimg, cosT, sinT);
  flash_attn_v12<<<512, 1024, 0, stream>>>(qb, Kimg, Vimg, qb);
  gemm_wo<<<dim3(8, 64), 256, 0, stream>>>(qb, wot, out);
}

// Round 8
// 165.244 us; speedup vs baseline: 1.0107x; 1.0022x over previous
//
#include <hip/hip_runtime.h>
#include <math.h>

#define S_LEN 2048
#define B_SZ 2

typedef __bf16 bf16_8 __attribute__((ext_vector_type(8)));
typedef float  f32_4  __attribute__((ext_vector_type(4)));

__device__ __forceinline__ unsigned short ftob(float f) {
  union { __bf16 h; unsigned short u; } cv;
  cv.h = (__bf16)f;              // fptrunc -> RNE
  return cv.u;
}

// async global->LDS, 16B per lane. LDS dest must be wave-uniform base + lane*16.
__device__ __forceinline__ void gll16(const unsigned short* g, unsigned short* l) {
  __builtin_amdgcn_global_load_lds(
      (const __attribute__((address_space(1))) unsigned int*)g,
      (__attribute__((address_space(3))) unsigned int*)l, 16, 0, 0);
}

// fold 1/sqrt(64) * log2(e) into Q at projection -> softmax in exp2 domain
#define QSCALE (0.125f * 1.44269504f)

// K/V tile images: dense 64x64 bf16 (4096 shorts = 8 KB), 16B-chunk XOR
// swizzle: element (row, col) at row*64 + ((col>>3) ^ (row&7))*8 + (col&7).
// V image rows = d, cols = key (natural order).
// K image rows are PERMUTED keys: image row mt*16 + q*4 + r holds key
// 32*(mt>>1) + q*8 + (mt&1)*4 + r -> QK^T C-layout packs directly into the
// PV B-frag layout lane-locally (no P LDS roundtrip).

// ---------------------------------------------------------------------------
// 32x32 transpose+convert tile helper: W[K=1024][N] fp32 -> Wt[N][1024] bf16.
// ---------------------------------------------------------------------------
__device__ __forceinline__ void tr_tile(const float* __restrict__ W,
                                        unsigned short* __restrict__ Wt,
                                        int N, int bx, int by, float (*T)[33])
{
  const int k0 = by * 32, n0 = bx * 32;
  const int r = threadIdx.x >> 3, c4 = (threadIdx.x & 7) * 4;
  const float4 v = *(const float4*)&W[(size_t)(k0 + r) * N + n0 + c4];
  T[r][c4 + 0] = v.x; T[r][c4 + 1] = v.y;
  T[r][c4 + 2] = v.z; T[r][c4 + 3] = v.w;
  __syncthreads();
  ushort4 o;
  o.x = ftob(T[c4 + 0][r]); o.y = ftob(T[c4 + 1][r]);
  o.z = ftob(T[c4 + 2][r]); o.w = ftob(T[c4 + 3][r]);
  *(ushort4*)&Wt[(size_t)(n0 + r) * 1024 + k0 + c4] = o;
}

// ---------------------------------------------------------------------------
// prep: [0,1024) wq->wqkvt | [1024,1280) wk | [1280,1536) wv |
//       [1536,2560) wo->wot | [2560,3584) x fp32->bf16
// ---------------------------------------------------------------------------
__global__ __launch_bounds__(256) void prep(
    const float* __restrict__ x, const float* __restrict__ wq,
    const float* __restrict__ wk, const float* __restrict__ wv,
    const float* __restrict__ wo,
    unsigned short* __restrict__ xb, unsigned short* __restrict__ wqkvt,
    unsigned short* __restrict__ wot)
{
  __shared__ float T[32][33];
  const int idx = blockIdx.x;
  if (idx < 1024) {
    tr_tile(wq, wqkvt, 1024, idx & 31, idx >> 5, T);
  } else if (idx < 1280) {
    const int i = idx - 1024;
    tr_tile(wk, wqkvt + 1024 * 1024, 256, i & 7, i >> 3, T);
  } else if (idx < 1536) {
    const int i = idx - 1280;
    tr_tile(wv, wqkvt + 1280 * 1024, 256, i & 7, i >> 3, T);
  } else if (idx < 2560) {
    const int i = idx - 1536;
    tr_tile(wo, wot, 1024, i & 31, i >> 5, T);
  } else {
    const int i = idx - 2560;
#pragma unroll
    for (int j = 0; j < 4; ++j) {
      const int id = i * 1024 + (int)threadIdx.x + j * 256;
      const float4 v = ((const float4*)x)[id];
      ushort4 o;
      o.x = ftob(v.x); o.y = ftob(v.y); o.z = ftob(v.z); o.w = ftob(v.w);
      ((ushort4*)xb)[id] = o;
    }
  }
}

// ---------------------------------------------------------------------------
// 64x128 GEMM core v2: BK=64 (two BK=32 panels), double-buffered LDS,
// COUNTED-vmcnt pipeline (T4) + source-side XOR bank swizzle (T2).
//  - raw s_barrier pairs instead of __syncthreads: the 6 prefetch loads stay
//    in flight across barriers; vmcnt(6) waits only for the CURRENT buffer's
//    DMA (never drains to 0 in the loop - m218's lever).
//  - barrier A (after lgkmcnt(0) fence, rule #18): all waves finished reading
//    buf c^1 -> safe to re-stage it. barrier B (after vmcnt(6)): every wave's
//    buf-c DMA landed -> safe to read.
//  - swizzle: LDS slot (row, chunk q) holds global chunk q^(row&3); gll16
//    dest stays LINEAR (rule #21), the source address carries the swizzle.
//    Reads use sq = quad ^ (l16&3): spreads the 64B-stride row reads from
//    2 banksets/quad (8-way, the m98 conflict) to 4+ sets.
// Buffer layout (shorts, per 12288-buf): [0,2048) A k0 | [2048,4096) A k1 |
// [4096,8192) B k0 (128 rows) | [8192,12288) B k1.
// ---------------------------------------------------------------------------
#define G64DB_STAGE(A_, B_, bo_, k0_)                                           \
  do {                                                                          \
    const int r = tid >> 2;                                                     \
    const int o8 = (((tid & 3) ^ (r & 3)) * 8);                                 \
    gll16(&A_[(size_t)(bm + r) * 1024 + (k0_) + o8], &sm[(bo_) + tid * 8]);     \
    gll16(&A_[(size_t)(bm + r) * 1024 + (k0_) + 32 + o8],                       \
          &sm[(bo_) + 2048 + tid * 8]);                                         \
    gll16(&B_[(size_t)(bn0 * 128 + r) * 1024 + (k0_) + o8],                     \
          &sm[(bo_) + 4096 + tid * 8]);                                         \
    gll16(&B_[(size_t)(bn0 * 128 + r + 64) * 1024 + (k0_) + o8],                \
          &sm[(bo_) + 6144 + tid * 8]);                                         \
    gll16(&B_[(size_t)(bn0 * 128 + r) * 1024 + (k0_) + 32 + o8],                \
          &sm[(bo_) + 8192 + tid * 8]);                                         \
    gll16(&B_[(size_t)(bn0 * 128 + r + 64) * 1024 + (k0_) + 32 + o8],           \
          &sm[(bo_) + 10240 + tid * 8]);                                        \
  } while (0)

#define G64DB_KLOOP(A_, B_)                                                     \
  G64DB_STAGE(A_, B_, 0, 0);                                                    \
  for (int s = 0; s < 16; ++s) {                                                \
    const int bo = (s & 1) * 12288;                                             \
    asm volatile("s_waitcnt lgkmcnt(0)" ::: "memory");                          \
    __builtin_amdgcn_sched_barrier(0);                                          \
    __builtin_amdgcn_s_barrier();   /* A: prev reads of buf c^1 done */         \
    __builtin_amdgcn_sched_barrier(0);                                          \
    if (s < 15) {                                                               \
      G64DB_STAGE(A_, B_, bo ^ 12288, (s + 1) * 64);                            \
      asm volatile("s_waitcnt vmcnt(6)" ::: "memory");  /* buf c landed */      \
    } else {                                                                    \
      asm volatile("s_waitcnt vmcnt(0)" ::: "memory");                          \
    }                                                                           \
    __builtin_amdgcn_sched_barrier(0);                                          \
    __builtin_amdgcn_s_barrier();   /* B: buf c valid for all waves */          \
    __builtin_amdgcn_sched_barrier(0);                                          \
    const int sq = quad ^ (l16 & 3);                                            \
    bf16_8 af[2][2], bf[2][4];                                                  \
    _Pragma("unroll")                                                           \
    for (int ks = 0; ks < 2; ++ks) {                                            \
      _Pragma("unroll")                                                         \
      for (int mt = 0; mt < 2; ++mt)                                            \
        af[ks][mt] = *(const bf16_8*)&sm[bo + ks * 2048 +                       \
                                         (mh + mt * 16 + l16) * 32 + sq * 8];   \
      _Pragma("unroll")                                                         \
      for (int nt = 0; nt < 4; ++nt)                                            \
        bf[ks][nt] = *(const bf16_8*)&sm[bo + 4096 + ks * 4096 +                \
                                         (nh + nt * 16 + l16) * 32 + sq * 8];   \
    }                                                                           \
    _Pragma("unroll")                                                           \
    for (int ks = 0; ks < 2; ++ks)                                              \
      _Pragma("unroll")                                                         \
      for (int mt = 0; mt < 2; ++mt)                                            \
        _Pragma("unroll")                                                       \
        for (int nt = 0; nt < 4; ++nt)                                          \
          acc[mt][nt] = __builtin_amdgcn_mfma_f32_16x16x32_bf16(                \
              af[ks][mt], bf[ks][nt], acc[mt][nt], 0, 0, 0);                    \
  }

// ---------------------------------------------------------------------------
// Fused QKV GEMM: [4096][1536] = xb @ wqkvt^T. BM=64, BN=128, grid (12,64).
// Epilogue: bn0 0..7 Q rope+scale -> qb; 8..9 K rope -> Kimg (PERMUTED rows,
// swizzled); 10..11 V -> LDS transpose -> Vimg (swizzled, b128 stores).
// ---------------------------------------------------------------------------
__global__ __launch_bounds__(256, 3) void gemm_qkv(
    const unsigned short* __restrict__ A, const unsigned short* __restrict__ Bt,
    unsigned short* __restrict__ qb, unsigned short* __restrict__ Kimg,
    unsigned short* __restrict__ Vimg,
    const float* __restrict__ cosT, const float* __restrict__ sinT)
{
  __shared__ unsigned short sm[24576];  // 2x12288 staging; V-epilogue reuses [0,9216)
  const int bm = blockIdx.y * 64, bn0 = blockIdx.x;
  const int tid = threadIdx.x;
  const int w = tid >> 6, lane = tid & 63, l16 = lane & 15, quad = lane >> 4;
  const int mh = (w & 1) * 32, nh = (w >> 1) * 64;

  f32_4 acc[2][4];
#pragma unroll
  for (int mt = 0; mt < 2; ++mt)
#pragma unroll
    for (int nt = 0; nt < 4; ++nt) acc[mt][nt] = (f32_4){0.f, 0.f, 0.f, 0.f};

  G64DB_KLOOP(A, Bt);

  const int colbase = bn0 * 128;
  if (colbase < 1024) {            // ---- Q: rope + scale ----
#pragma unroll
    for (int mt = 0; mt < 2; ++mt)
#pragma unroll
      for (int r = 0; r < 4; ++r) {
        const int row = bm + mh + mt * 16 + quad * 4 + r;
        const int s = row & (S_LEN - 1);
#pragma unroll
        for (int nt = 0; nt < 4; ++nt) {
          const int col = colbase + nh + nt * 16 + l16;
          float val = acc[mt][nt][r];
          const float pv = __shfl_xor(val, 1);
          const int fi = (col & 63) >> 1;
          const float cc = cosT[s * 32 + fi], ss = sinT[s * 32 + fi];
          val = (l16 & 1) ? fmaf(pv, ss, val * cc) : fmaf(val, cc, -(pv * ss));
          qb[(size_t)row * 1024 + col] = ftob(val * QSCALE);
        }
      }
  } else if (colbase < 1280) {     // ---- K: rope -> permuted+swizzled image ----
#pragma unroll
    for (int mt = 0; mt < 2; ++mt)
#pragma unroll
      for (int r = 0; r < 4; ++r) {
        const int row = bm + mh + mt * 16 + quad * 4 + r;
        const int s = row & (S_LEN - 1), bi = row >> 11;
        const int tile = s >> 6, key = s & 63;
        // permuted image row: row mt*16+q*4+rr holds key 32*(mt>>1)+q*8+(mt&1)*4+rr
        const int kk = key & 31, jj = kk & 7;
        const int rowp = ((key >> 5) << 5) + ((jj >> 2) << 4) + ((kk >> 3) << 2) + (jj & 3);
#pragma unroll
        for (int nt = 0; nt < 4; ++nt) {
          const int col = colbase + nh + nt * 16 + l16;
          float val = acc[mt][nt][r];
          const float pv = __shfl_xor(val, 1);
          const int fi = (col & 63) >> 1;
          const float cc = cosT[s * 32 + fi], ss = sinT[s * 32 + fi];
          val = (l16 & 1) ? fmaf(pv, ss, val * cc) : fmaf(val, cc, -(pv * ss));
          const int gcol = col - 1024, g = gcol >> 6, d = gcol & 63;
          Kimg[(size_t)((bi * 4 + g) * 32 + tile) * 4096 + rowp * 64 +
               (((d >> 3) ^ (rowp & 7)) * 8) + (d & 7)] = ftob(val);
        }
      }
  } else {                         // ---- V: LDS transpose -> swizzled image ----
    const int bi = bm >> 11, t0 = (bm & 2047) >> 6;
    const int gp = (bn0 - 10) * 2;
    __syncthreads();               // staging reads done before sm reuse
    {
      // wave w covers group gp + (w>>1), keys mh..mh+31, d 0..63
      unsigned short* Ts = sm + (w >> 1) * 4608;   // [64 d][72]
#pragma unroll
      for (int mt = 0; mt < 2; ++mt)
#pragma unroll
        for (int nt = 0; nt < 4; ++nt) {
          const int keyb = mh + mt * 16 + quad * 4;  // 4 consecutive keys
          const int d = nt * 16 + l16;
          ushort4 pk;
#pragma unroll
          for (int r = 0; r < 4; ++r) ((unsigned short*)&pk)[r] = ftob(acc[mt][nt][r]);
          *(ushort4*)&Ts[d * 72 + keyb] = pk;
        }
    }
    __syncthreads();
#pragma unroll
    for (int it = 0; it < 4; ++it) {
      const int c = tid + it * 256;              // 1024 chunks: 2 imgs x 512
      const int img = c >> 9, cc = c & 511;
      const int d = cc >> 3, ch = cc & 7;
      const uint4 v = *(const uint4*)&sm[img * 4608 + d * 72 + ch * 8];
      *(uint4*)&Vimg[(size_t)((bi * 4 + gp + img) * 32 + t0) * 4096 + d * 64 +
                     ((ch ^ (d & 7)) * 8)] = v;
    }
  }
}

// ---------------------------------------------------------------------------
// Output GEMM: out[4096][1024] fp32 = attn @ wot^T. BM=64, BN=128, grid (8,64).
// ---------------------------------------------------------------------------
__global__ __launch_bounds__(256, 2) void gemm_wo(
    const unsigned short* __restrict__ A, const unsigned short* __restrict__ Bt,
    float* __restrict__ C)
{
  __shared__ unsigned short sm[24576];
  const int bm = blockIdx.y * 64, bn0 = blockIdx.x;
  const int tid = threadIdx.x;
  const int w = tid >> 6, lane = tid & 63, l16 = lane & 15, quad = lane >> 4;
  const int mh = (w & 1) * 32, nh = (w >> 1) * 64;

  f32_4 acc[2][4];
#pragma unroll
  for (int mt = 0; mt < 2; ++mt)
#pragma unroll
    for (int nt = 0; nt < 4; ++nt) acc[mt][nt] = (f32_4){0.f, 0.f, 0.f, 0.f};

  G64DB_KLOOP(A, Bt);

#pragma unroll
  for (int mt = 0; mt < 2; ++mt)
#pragma unroll
    for (int r = 0; r < 4; ++r) {
      const int row = bm + mh + mt * 16 + quad * 4 + r;
#pragma unroll
      for (int nt = 0; nt < 4; ++nt)
        C[(size_t)row * 1024 + bn0 * 128 + nh + nt * 16 + l16] = acc[mt][nt][r];
    }
}

// ---------------------------------------------------------------------------
// Flash attention v12 (unchanged from round 7): 4-way key split in one
// 1024-thread block (16 waves = 4 heads x 4 key-quarters), two-phase snake
// scheduling, Ps-free permuted-K packing, dbuf DMA staging.
// ---------------------------------------------------------------------------
__global__ __launch_bounds__(1024, 4) void flash_attn_v12(
    const unsigned short* __restrict__ Q, const unsigned short* __restrict__ Kimg,
    const unsigned short* __restrict__ Vimg, unsigned short* __restrict__ O)
{
  __shared__ unsigned short KV[2][32768];  // [buf][ K 4x4096 | V 4x4096 ] shorts
  __shared__ float lbuf[12][2][64];
  const int id = blockIdx.x;
  const int gb = id & 7;                       // b*4+g -> XCD pin
  const int g = gb & 3, b = gb >> 2;
  const int i = id >> 3;                       // 0..63
  const int qc = (i < 32) ? (32 + i) : (63 - i);   // two-phase snake
  const int tid = threadIdx.x;
  const int w = tid >> 6, lane = tid & 63, l16 = lane & 15, quad = lane >> 4;
  const int hw = w & 3, p = w >> 2;            // head-in-group, key quarter
  const int h = g * 4 + hw;
  const int qbase = qc * 32;
  const int swz = l16 & 7;

  // Q B-frags (register-resident): n = q = l16 (+16*qf), k = d = quad*8+j
  bf16_8 bq[2][2];
#pragma unroll
  for (int qf = 0; qf < 2; ++qf) {
    const unsigned short* qp =
        Q + ((size_t)(b * S_LEN + qbase + qf * 16 + l16)) * 1024 + h * 64;
    bq[qf][0] = *(const bf16_8*)(qp + quad * 8);
    bq[qf][1] = *(const bf16_8*)(qp + 32 + quad * 8);
  }

  f32_4 acc[2][4];
  float l_part[2] = {0.f, 0.f};
#pragma unroll
  for (int qf = 0; qf < 2; ++qf)
#pragma unroll
    for (int mt = 0; mt < 4; ++mt) acc[qf][mt] = (f32_4){0.f, 0.f, 0.f, 0.f};

  const unsigned short* kim = Kimg + (size_t)(gb * 32) * 4096;
  const unsigned short* vim = Vimg + (size_t)(gb * 32) * 4096;
  const int ntiles = (qc >> 1) + 1;
  const int steps = (ntiles + 3) >> 2;
  const int hq = (qc & 1) * 32;                // q offset within diag tile

  // stage 4 tiles (32 KB K + 32 KB V) into buf c_; 4 gll16/thread.
#define FA12_STAGE(s_, c_)                                                      \
  do {                                                                          \
    const unsigned short* kp = kim + (size_t)(s_) * 16384;                      \
    const unsigned short* vp = vim + (size_t)(s_) * 16384;                      \
    gll16(kp + tid * 8, &KV[c_][tid * 8]);                                      \
    gll16(kp + (tid + 1024) * 8, &KV[c_][(tid + 1024) * 8]);                    \
    gll16(vp + tid * 8, &KV[c_][16384 + tid * 8]);                              \
    gll16(vp + (tid + 1024) * 8, &KV[c_][16384 + (tid + 1024) * 8]);            \
  } while (0)

  FA12_STAGE(0, 0);
  for (int s = 0; s < steps; ++s) {
    const int c = s & 1;
    __syncthreads();                   // own vmcnt drained -> buf c ready;
                                       // prev readers of buf c^1 also done
    if (s + 1 < steps) FA12_STAGE(s + 1, c ^ 1);

    const int tile = 4 * s + p;
    if (tile < ntiles) {
      const bool diag = (tile == ntiles - 1);
      const unsigned short* ks = &KV[c][p * 4096];
      const unsigned short* vs = &KV[c][16384 + p * 4096];
      // ---- S^T = K Q^T; p = exp2(s); pack DIRECTLY into PV B-frags ----
      union { bf16_8 v; unsigned int wd[4]; } pf[2][2];
#pragma unroll
      for (int mt = 0; mt < 4; ++mt) {
        const int krow = (mt * 16 + l16) * 64;
        const bf16_8 kf0 = *(const bf16_8*)&ks[krow + (quad ^ swz) * 8];
        const bf16_8 kf1 = *(const bf16_8*)&ks[krow + ((4 + quad) ^ swz) * 8];
#pragma unroll
        for (int qf = 0; qf < 2; ++qf) {
          f32_4 z = (f32_4){0.f, 0.f, 0.f, 0.f};
          __builtin_amdgcn_s_setprio(1);
          z = __builtin_amdgcn_mfma_f32_16x16x32_bf16(kf0, bq[qf][0], z, 0, 0, 0);
          z = __builtin_amdgcn_mfma_f32_16x16x32_bf16(kf1, bq[qf][1], z, 0, 0, 0);
          __builtin_amdgcn_s_setprio(0);
          float pv[4];
#pragma unroll
          for (int r = 0; r < 4; ++r) {
            float pe = __builtin_amdgcn_exp2f(z[r]);
            if (diag) {
              // actual key of z[mt] reg r (permuted rows):
              const int keyl = ((mt >> 1) << 5) + quad * 8 + ((mt & 1) << 2) + r;
              const int ql = hq + qf * 16 + l16;
              pe = (keyl > ql) ? 0.f : pe;
            }
            l_part[qf] += pe;
            pv[r] = pe;
          }
          pf[qf][mt >> 1].wd[(mt & 1) * 2 + 0] =
              (unsigned int)ftob(pv[0]) | ((unsigned int)ftob(pv[1]) << 16);
          pf[qf][mt >> 1].wd[(mt & 1) * 2 + 1] =
              (unsigned int)ftob(pv[2]) | ((unsigned int)ftob(pv[3]) << 16);
        }
      }
      // ---- O^T += V^T @ P^T (pf straight from registers) ----
      __builtin_amdgcn_s_setprio(1);
#pragma unroll
      for (int mt = 0; mt < 4; ++mt) {
        const int vrow = (mt * 16 + l16) * 64;
        const bf16_8 vf0 = *(const bf16_8*)&vs[vrow + (quad ^ swz) * 8];
        const bf16_8 vf1 = *(const bf16_8*)&vs[vrow + ((4 + quad) ^ swz) * 8];
#pragma unroll
        for (int qf = 0; qf < 2; ++qf) {
          acc[qf][mt] = __builtin_amdgcn_mfma_f32_16x16x32_bf16(vf0, pf[qf][0].v, acc[qf][mt], 0, 0, 0);
          acc[qf][mt] = __builtin_amdgcn_mfma_f32_16x16x32_bf16(vf1, pf[qf][1].v, acc[qf][mt], 0, 0, 0);
        }
      }
      __builtin_amdgcn_s_setprio(0);
    }
  }

  // ---- combine quarter partials (linear; no running max) ----
  __syncthreads();                             // all compute done; KV reusable
  float* cb = (float*)&KV[0][0];               // 12 slots x 2048 f32 = 96 KB
  if (p != 0) {
    const int slot = (p - 1) * 4 + hw;
    float* dst = cb + slot * 2048;
#pragma unroll
    for (int qf = 0; qf < 2; ++qf)
#pragma unroll
      for (int mt = 0; mt < 4; ++mt)
#pragma unroll
        for (int r = 0; r < 4; ++r)
          dst[(qf * 16 + mt * 4 + r) * 64 + lane] = acc[qf][mt][r];
    lbuf[slot][0][lane] = l_part[0];
    lbuf[slot][1][lane] = l_part[1];
  }
  __syncthreads();
  if (p == 0) {
#pragma unroll
    for (int pp = 0; pp < 3; ++pp) {
      const int slot = pp * 4 + hw;
      const float* src = cb + slot * 2048;
#pragma unroll
      for (int qf = 0; qf < 2; ++qf)
#pragma unroll
        for (int mt = 0; mt < 4; ++mt)
#pragma unroll
          for (int r = 0; r < 4; ++r)
            acc[qf][mt][r] += src[(qf * 16 + mt * 4 + r) * 64 + lane];
      l_part[0] += lbuf[slot][0][lane];
      l_part[1] += lbuf[slot][1][lane];
    }

    // ---- finalize: l = sum over quads (keys partitioned by quad) ----
#pragma unroll
    for (int qf = 0; qf < 2; ++qf) {
      float l = l_part[qf];
      l += __shfl_xor(l, 16);
      l += __shfl_xor(l, 32);
      const float inv = 1.f / l;
      unsigned short* op =
          O + ((size_t)(b * S_LEN + qbase + qf * 16 + l16)) * 1024 + h * 64;
#pragma unroll
      for (int mt = 0; mt < 4; ++mt) {
        ushort4 ov;
#pragma unroll
        for (int r = 0; r < 4; ++r) ((unsigned short*)&ov)[r] = ftob(acc[qf][mt][r] * inv);
        *(ushort4*)&op[mt * 16 + quad * 4] = ov;
      }
    }
  }
}

// ---------------------------------------------------------------------------
extern "C" void kernel_launch(void* const* d_in, const int* in_sizes, int n_in,
                              void* d_out, int out_size, void* d_ws, size_t ws_size,
                              hipStream_t stream)
{
  const float* x    = (const float*)d_in[0];
  const float* cosT = (const float*)d_in[1];
  const float* sinT = (const float*)d_in[2];
  const float* wq   = (const float*)d_in[4];
  const float* wk   = (const float*)d_in[5];
  const float* wv   = (const float*)d_in[6];
  const float* wo   = (const float*)d_in[7];
  float* out = (float*)d_out;

  char* ws = (char*)d_ws;
  const size_t MB = 1024 * 1024;
  unsigned short* xb    = (unsigned short*)(ws);             // 8 MB
  unsigned short* qb    = (unsigned short*)(ws + 8 * MB);    // 8 MB [4096][1024]
  unsigned short* wqkvt = (unsigned short*)(ws + 16 * MB);   // 3 MB [1536][1024]
  unsigned short* Kimg  = (unsigned short*)(ws + 19 * MB);   // 2 MB (permuted+swizzled)
  unsigned short* Vimg  = (unsigned short*)(ws + 21 * MB);   // 2 MB (swizzled)
  unsigned short* wot   = (unsigned short*)(ws + 23 * MB);   // 2 MB [1024][1024]
  // total ws use: 25 MB

  prep<<<3584, 256, 0, stream>>>(x, wq, wk, wv, wo, xb, wqkvt, wot);
  gemm_qkv<<<dim3(12, 64), 256, 0, stream>>>(xb, wqkvt, qb, Kimg, Vimg, cosT, sinT);
  flash_attn_v12<<<512, 1024, 0, stream>>>(qb, Kimg, Vimg, qb);
  gemm_wo<<<dim3(8, 64), 256, 0, stream>>>(qb, wot, out);
}